// Round 6
// baseline (98.160 us; speedup 1.0000x reference)
//
#include <hip/hip_runtime.h>
#include <math.h>

// Density-Aware Chamfer Loss, B=4, N=8192, fp32 3D points.
//
// Round-23: REVERT r22's QPB=1024 (97.4us: 2 blocks/CU occupancy loss beat
// the staging savings) back to the verified r19 shape (QPB=512, 4 blocks/CU,
// 96.46us, absmax 0.0), plus ONE variable — vectorize partial's target
// staging: 12 scalar dword loads/thread -> 3 float4 loads/thread (thread
// tid takes 4 consecutive targets = 48B contiguous; G13).  Same bytes, same
// pack math, identical frag contents -> absmax must stay 0.0.
//
// Structure: MFMA 32x32x16 bf16 hi/lo split (K=13 of 16) exact-form distance
// tiles; per-slice min+tile keys (value24|tile5, group OR'd at scan) ->
// slot rows; merge: A1 coalesced 8-row uint scan (ties -> lowest group then
// tile) + A2 exact 32-target rescan, 4 workers/query, named float4,
// first-min tie-break = jnp.argmin; loss: exact d (2^-16 trunc) + final cnt.
// No grid-wide sync anywhere (coop fusion measured 437us in r21 — dead end).
//
// ws: [slot 8grp x 2BN u32-key (2.1MB)][cnt 2BN int]
// Dispatches: partial(+zero cnt) -> merge(+zero out) -> loss.   (3 total)

#define NPTS   8192
#define BLK    256
#define QPB    512                  // queries per block (partial; 4 waves x 4x32)
#define TPS    1024                 // targets per slice (32KB LDS A-frags)
#define TILES  (TPS / 32)           // 32 MFMA tiles per slice
#define NSLICE (NPTS / TPS)         // 8
#define QCH    (NPTS / QPB)         // 16
#define GRP    1024                 // targets per slot group (= slice)
#define NGRP   (NPTS / GRP)         // 8
#define FQ     64                   // queries per merge block

typedef __attribute__((ext_vector_type(8)))  short short8;
typedef __attribute__((ext_vector_type(16))) float float16v;

__device__ inline void bsplit(float x, unsigned short& h, unsigned short& l) {
    const unsigned int u = __float_as_uint(x);
    const unsigned short hh = (unsigned short)(u >> 16);   // truncated bf16 hi
    const float lf = x - __uint_as_float((unsigned int)hh << 16);
    h = hh;
    l = (unsigned short)(__float_as_uint(lf) >> 16);       // bf16 lo
}

__device__ inline short8 make_bfrag(float qx, float qy, float qz, int khalf) {
    const float q2 = fmaf(qx, qx, fmaf(qy, qy, qz * qz));
    unsigned short shx, slx, shy, sly, shz, slz, h2q, l2q;
    bsplit(-2.0f * qx, shx, slx); bsplit(-2.0f * qy, shy, sly);
    bsplit(-2.0f * qz, shz, slz); bsplit(q2, h2q, l2q);
    union { short8 v; unsigned short s[8]; } bu;
    if (khalf == 0) {
        bu.s[0]=shx; bu.s[1]=shy; bu.s[2]=shz; bu.s[3]=slx; bu.s[4]=sly; bu.s[5]=slz; bu.s[6]=shx; bu.s[7]=shy;
    } else {
        bu.s[0]=shz; bu.s[1]=0x3F80; bu.s[2]=0x3F80; bu.s[3]=h2q; bu.s[4]=l2q; bu.s[5]=0; bu.s[6]=0; bu.s[7]=0;
    }
    return bu.v;
}

__device__ inline float tree16(const float16v& a) {
    const float t0 = fminf(fminf(a[0],  a[1]),  a[2]);
    const float t1 = fminf(fminf(a[3],  a[4]),  a[5]);
    const float t2 = fminf(fminf(a[6],  a[7]),  a[8]);
    const float t3 = fminf(fminf(a[9],  a[10]), a[11]);
    const float t4 = fminf(fminf(a[12], a[13]), a[14]);
    return fminf(fminf(fminf(t0, t1), a[15]), fminf(fminf(t2, t3), t4));
}

// monotone key: sign-flip map, trunc to 24 value bits, tile id in [4:0].
// bits [7:5] left zero for the group (slice) id (OR'd in by merge A1).
__device__ inline unsigned int packkey(float g, int tl) {
    unsigned int u = __float_as_uint(g);
    u = ((int)u < 0) ? ~u : (u | 0x80000000u);
    return (u & 0xFFFFFF00u) | (unsigned int)tl;
}

// pack one target (tx,ty,tz) into its two k-half frag rows
__device__ inline void pack_target(short8* frag, int tgt,
                                   float tx, float ty, float tz) {
    const float t2 = fmaf(tx, tx, fmaf(ty, ty, tz * tz));
    unsigned short hx, lx, hy, ly, hz, lz, h2, l2;
    bsplit(tx, hx, lx); bsplit(ty, hy, ly); bsplit(tz, hz, lz); bsplit(t2, h2, l2);
    union { short8 v; unsigned short s[8]; } k0, k1;
    k0.s[0]=hx; k0.s[1]=hy; k0.s[2]=hz; k0.s[3]=hx; k0.s[4]=hy; k0.s[5]=hz; k0.s[6]=lx; k0.s[7]=ly;
    k1.s[0]=lz; k1.s[1]=h2; k1.s[2]=l2; k1.s[3]=0x3F80; k1.s[4]=0x3F80; k1.s[5]=0; k1.s[6]=0; k1.s[7]=0;
    const int tile = tgt >> 5, row = tgt & 31;
    frag[tile * 64 + row]      = k0.v;                     // k-half 0 (lanes 0-31)
    frag[tile * 64 + 32 + row] = k1.v;                     // k-half 1 (lanes 32-63)
}

__global__ __launch_bounds__(BLK, 4) void dacl_partial(
    const float* __restrict__ gts, const float* __restrict__ preds,
    float* __restrict__ slot, int* __restrict__ cnt, int B, int N)
{
    const int bz  = blockIdx.z;      // dir*B + b
    const int dir = bz / B;
    const int b   = bz - dir * B;
    const int total = 2 * B * N;

    // fold cnt zeroing in (first read by dacl_merge -> boundary orders)
    if (blockIdx.y == 0) {
        const int per = total / (QCH * 2 * B);             // 512
        int* p = cnt + (blockIdx.x + QCH * bz) * per;
        for (int k = threadIdx.x; k < per; k += BLK) p[k] = 0;
    }

    const float* __restrict__ q = (dir == 0 ? gts : preds) + (size_t)b * N * 3;
    const float* __restrict__ t = (dir == 0 ? preds : gts) + (size_t)b * N * 3;

    __shared__ short8 frag[TILES * 64];                    // 32KB A-frags

    // stage+pack A-frags: 1024 targets, 4 consecutive per thread via 3 x
    // float4 (48B contiguous per thread; wave-contiguous dwordx4 stream).
    // MFMA K=13 layout: k0-2 thi.(-2qhi)  k3-5 thi.(-2qlo)  k6-8 tlo.(-2qhi)
    // k9 |t|^2hi.1  k10 |t|^2lo.1  k11 1.|q|^2hi  k12 1.|q|^2lo
    {
        const int sbase = blockIdx.y * TPS;
        const float4* __restrict__ t4 =
            (const float4*)(t + (size_t)sbase * 3) + threadIdx.x * 3;
        const float4 v0 = t4[0];     // t0.xyz  t1.x
        const float4 v1 = t4[1];     // t1.yz   t2.xy
        const float4 v2 = t4[2];     // t2.z    t3.xyz
        const int tgt0 = threadIdx.x * 4;
        pack_target(frag, tgt0 + 0, v0.x, v0.y, v0.z);
        pack_target(frag, tgt0 + 1, v0.w, v1.x, v1.y);
        pack_target(frag, tgt0 + 2, v1.z, v1.w, v2.x);
        pack_target(frag, tgt0 + 3, v2.y, v2.z, v2.w);
    }

    // four B-frags per wave: query cols qiA, +128, +256, +384
    const int lane = threadIdx.x & 63;
    const int wave = threadIdx.x >> 6;
    const int kh   = lane >> 5;
    const int qiA  = blockIdx.x * QPB + wave * 32 + (lane & 31);
    const int qiB  = qiA + 128;
    const int qiC  = qiA + 256;
    const int qiD  = qiA + 384;
    const short8 bfragA = make_bfrag(q[3*qiA], q[3*qiA+1], q[3*qiA+2], kh);
    const short8 bfragB = make_bfrag(q[3*qiB], q[3*qiB+1], q[3*qiB+2], kh);
    const short8 bfragC = make_bfrag(q[3*qiC], q[3*qiC+1], q[3*qiC+2], kh);
    const short8 bfragD = make_bfrag(q[3*qiD], q[3*qiD+1], q[3*qiD+2], kh);

    __syncthreads();

    const float16v zz = {0.f,0.f,0.f,0.f, 0.f,0.f,0.f,0.f,
                         0.f,0.f,0.f,0.f, 0.f,0.f,0.f,0.f};
    const size_t gqA = (size_t)bz * N + qiA;
    unsigned int* __restrict__ slotU = (unsigned int*)slot;
    float gminA = 3.402823466e38f, gminB = 3.402823466e38f;
    float gminC = 3.402823466e38f, gminD = 3.402823466e38f;
    int tlA = 0, tlB = 0, tlC = 0, tlD = 0;

    // hot loop: 1 ds_read_b128 + 4 independent MFMA + 4 min trees per tile;
    // strict-less tile tracking keeps the FIRST (lowest) min tile.
    #pragma unroll 2
    for (int tile = 0; tile < TILES; ++tile) {
        const short8 av = frag[tile * 64 + lane];
        const float16v aA = __builtin_amdgcn_mfma_f32_32x32x16_bf16(av, bfragA, zz, 0, 0, 0);
        const float16v aB = __builtin_amdgcn_mfma_f32_32x32x16_bf16(av, bfragB, zz, 0, 0, 0);
        const float16v aC = __builtin_amdgcn_mfma_f32_32x32x16_bf16(av, bfragC, zz, 0, 0, 0);
        const float16v aD = __builtin_amdgcn_mfma_f32_32x32x16_bf16(av, bfragD, zz, 0, 0, 0);
        const float tA = tree16(aA);
        const float tB = tree16(aB);
        const float tC = tree16(aC);
        const float tD = tree16(aD);
        tlA = (tA < gminA) ? tile : tlA;  gminA = fminf(gminA, tA);
        tlB = (tB < gminB) ? tile : tlB;  gminB = fminf(gminB, tB);
        tlC = (tC < gminC) ? tile : tlC;  gminC = fminf(gminC, tC);
        tlD = (tD < gminD) ? tile : tlD;  gminD = fminf(gminD, tD);
    }

    // close the slice: pack keys, cross-k-half min, one coalesced row store
    {
        const size_t rbase = (size_t)blockIdx.y * total;
        const unsigned int kA = packkey(gminA, tlA);
        const unsigned int kB = packkey(gminB, tlB);
        const unsigned int kC = packkey(gminC, tlC);
        const unsigned int kD = packkey(gminD, tlD);
        const unsigned int oA = min(kA, (unsigned int)__shfl_xor((int)kA, 32, 64));
        const unsigned int oB = min(kB, (unsigned int)__shfl_xor((int)kB, 32, 64));
        const unsigned int oC = min(kC, (unsigned int)__shfl_xor((int)kC, 32, 64));
        const unsigned int oD = min(kD, (unsigned int)__shfl_xor((int)kD, 32, 64));
        if (lane < 32) {
            slotU[rbase + gqA]       = oA;
            slotU[rbase + gqA + 128] = oB;
            slotU[rbase + gqA + 256] = oC;
            slotU[rbase + gqA + 384] = oD;
        }
    }
}

__device__ inline float sq3(float x, float y, float z) {
    return fmaf(x, x, fmaf(y, y, z * z));
}

// 8 exact distances from 6 named float4 (12B per target) — no indexable array
#define DIST8(V0,V1,V2,V3,V4,V5,BASE)                                          \
    do {                                                                       \
        const float d0 = sq3(qx-(V0).x, qy-(V0).y, qz-(V0).z);                 \
        const float d1 = sq3(qx-(V0).w, qy-(V1).x, qz-(V1).y);                 \
        const float d2 = sq3(qx-(V1).z, qy-(V1).w, qz-(V2).x);                 \
        const float d3 = sq3(qx-(V2).y, qy-(V2).z, qz-(V2).w);                 \
        const float d4 = sq3(qx-(V3).x, qy-(V3).y, qz-(V3).z);                 \
        const float d5 = sq3(qx-(V3).w, qy-(V4).x, qz-(V4).y);                 \
        const float d6 = sq3(qx-(V4).z, qy-(V4).w, qz-(V5).x);                 \
        const float d7 = sq3(qx-(V5).y, qy-(V5).z, qz-(V5).w);                 \
        best = min(best, (__float_as_uint(d0) & 0xFFFFFF00u) | (unsigned)((BASE)+0)); \
        best = min(best, (__float_as_uint(d1) & 0xFFFFFF00u) | (unsigned)((BASE)+1)); \
        best = min(best, (__float_as_uint(d2) & 0xFFFFFF00u) | (unsigned)((BASE)+2)); \
        best = min(best, (__float_as_uint(d3) & 0xFFFFFF00u) | (unsigned)((BASE)+3)); \
        best = min(best, (__float_as_uint(d4) & 0xFFFFFF00u) | (unsigned)((BASE)+4)); \
        best = min(best, (__float_as_uint(d5) & 0xFFFFFF00u) | (unsigned)((BASE)+5)); \
        best = min(best, (__float_as_uint(d6) & 0xFFFFFF00u) | (unsigned)((BASE)+6)); \
        best = min(best, (__float_as_uint(d7) & 0xFFFFFF00u) | (unsigned)((BASE)+7)); \
    } while (0)

// A1 + A2 + count; 1024 blocks, 4 workers/query, NO barrier.
// A1: uint min over pre-packed keys | group<<5 -> lexicographic
// (value, group, tile) = first-min order.  A2: exact rescan of the winning
// 32-target tile only (6 float4 + 1 DIST8 per worker).
// Result reuse: d -> slot row 0, idxg -> slot row 1 (rows dead after A1).
__global__ __launch_bounds__(BLK) void dacl_merge(
    const float* __restrict__ gts, const float* __restrict__ preds,
    float* __restrict__ slot, int* __restrict__ cnt,
    float* __restrict__ out, int out_size, int B, int N)
{
    const int tid  = threadIdx.x;
    const int lane = tid & 63;       // local query 0..63
    const int wv   = tid >> 6;       // sub-worker 0..3
    const int total = 2 * B * N;
    const int g0   = blockIdx.x * FQ;                      // first query of block
    const int bz   = g0 / N;                               // block-uniform
    const int dir  = bz / B;
    const int b    = bz - dir * B;
    const float* __restrict__ q = (dir == 0 ? gts : preds) + (size_t)b * N * 3;
    const float* __restrict__ t = (dir == 0 ? preds : gts) + (size_t)b * N * 3;

    __shared__ unsigned int smin[FQ];   // A1: value24 | group3 | tile5
    __shared__ unsigned int skey[FQ];   // A2: bits(d)&~0xFF | idx8

    if (blockIdx.x == 0 && tid < out_size) out[tid] = 0.0f;
    if (tid < FQ) { smin[tid] = 0xFFFFFFFFu; skey[tid] = 0xFFFFFFFFu; }
    __syncthreads();

    const int g = g0 + lane;                               // this query id
    const unsigned int* __restrict__ slotU = (const unsigned int*)slot;

    // A1: wave wv scans group rows [wv*2, wv*2+2); coalesced per row
    {
        unsigned int pk = 0xFFFFFFFFu;
        #pragma unroll
        for (int s = wv * 2; s < wv * 2 + 2; ++s)
            pk = min(pk, slotU[(size_t)s * total + g] | ((unsigned int)s << 5));
        atomicMin(&smin[lane], pk);                        // LDS; ties -> low grp/tile
    }
    __syncthreads();
    const unsigned int sel = smin[lane];
    const int gr = (int)((sel >> 5) & 7u);
    const int tl = (int)(sel & 31u);

    // A2: 4 workers/query, 8 exact targets each over the winning 32-target tile
    const float qx = q[3 * (g - bz * N)], qy = q[3 * (g - bz * N) + 1],
                qz = q[3 * (g - bz * N) + 2];
    {
        const float4* __restrict__ tb4 =
            (const float4*)(t + (size_t)(gr * GRP + tl * 32) * 3) + wv * 6;
        unsigned int best = 0xFFFFFFFFu;
        const float4 v0 = tb4[0];
        const float4 v1 = tb4[1];
        const float4 v2 = tb4[2];
        const float4 v3 = tb4[3];
        const float4 v4 = tb4[4];
        const float4 v5 = tb4[5];
        DIST8(v0, v1, v2, v3, v4, v5, wv * 8);
        atomicMin(&skey[lane], best);                      // LDS; first-min idx
    }
    __syncthreads();

    if (tid < FQ) {
        const unsigned int key = skey[tid];
        const unsigned int sl  = smin[tid];
        const int idxg = (int)((sl >> 5) & 7u) * GRP + (int)(sl & 31u) * 32
                       + (int)(key & 255u);
        slot[g0 + tid]                 = __uint_as_float(key & 0xFFFFFF00u); // d
        ((int*)slot)[total + g0 + tid] = idxg;                               // idx
        atomicAdd(&cnt[bz * N + idxg], 1);
    }
}

__global__ __launch_bounds__(256) void dacl_loss(
    const float* __restrict__ slot, const int* __restrict__ cnt,
    float* __restrict__ out, int B, int N)
{
    const int g  = blockIdx.x * 256 + threadIdx.x;         // query id
    const int total = 2 * B * N;
    const int bz = g / N;
    const int b  = bz - (bz / B) * B;

    const float d   = slot[g];                             // exact (<=2^-16 trunc)
    const int   idx = ((const int*)slot)[total + g];
    const float c   = (float)cnt[bz * N + idx];            // count^1 (lambda=1)
    float sv = 1.0f - expf(-d) / (c + 1e-6f);              // frac terms = 1
    #pragma unroll
    for (int off = 32; off > 0; off >>= 1) sv += __shfl_down(sv, off, 64);
    if ((threadIdx.x & 63) == 0)
        atomicAdd(&out[b], sv / (2.0f * (float)N));        // (mean1+mean2)/2
}

extern "C" void kernel_launch(void* const* d_in, const int* in_sizes, int n_in,
                              void* d_out, int out_size, void* d_ws, size_t ws_size,
                              hipStream_t stream)
{
    const float* gts   = (const float*)d_in[0];
    const float* preds = (const float*)d_in[1];

    const int N = NPTS;
    const int B = in_sizes[0] / (N * 3);                   // = 4

    const size_t nTot = (size_t)2 * B * N;                 // 65536 queries
    float* slot = (float*)d_ws;                            // NGRP x nTot (2.1MB)
    int*   cnt  = (int*)((char*)d_ws + (size_t)NGRP * nTot * sizeof(float));

    dim3 gA(QCH, NSLICE, 2 * B);                           // 16 x 8 x 8 = 1024 blocks
    dacl_partial<<<gA, BLK, 0, stream>>>(gts, preds, slot, cnt, B, N);

    dacl_merge<<<(int)(nTot / FQ), BLK, 0, stream>>>(      // 1024 blocks
        gts, preds, slot, cnt, (float*)d_out, out_size, B, N);

    dacl_loss<<<(int)(nTot / 256), 256, 0, stream>>>(      // 256 blocks
        slot, cnt, (float*)d_out, B, N);
}

// Round 7
// 95.347 us; speedup vs baseline: 1.0295x; 1.0295x over previous
//
#include <hip/hip_runtime.h>
#include <math.h>

// Density-Aware Chamfer Loss, B=4, N=8192, fp32 3D points.
//
// Round-24: REVERT to r19 exactly (best measured: 96.46us, absmax 0.0).
// r22 (QPB=1024: 97.4), r23 (float4 staging: 98.2), r20/21 (coop fusion:
// 437) all regressed -> partial's staging is already hidden under the
// hot-loop VALU/MFMA at 4 blocks/CU; 3-dispatch structure is optimal.
// This restores the verified optimum unchanged.
//
// Structure: MFMA 32x32x16 bf16 hi/lo split (K=13 of 16) exact-form distance
// tiles; per-slice min+tile keys (value24|tile5, group OR'd at scan) ->
// slot rows; merge: A1 coalesced 8-row uint scan (ties -> lowest group then
// tile) + A2 exact 32-target rescan, 4 workers/query, named float4,
// first-min tie-break = jnp.argmin; loss: exact d (2^-16 trunc) + final cnt.
//
// ws: [slot 8grp x 2BN u32-key (2.1MB)][cnt 2BN int]
// Dispatches: partial(+zero cnt) -> merge(+zero out) -> loss.   (3 total)

#define NPTS   8192
#define BLK    256
#define QPB    512                  // queries per block (partial; 4 waves x 4x32)
#define TPS    1024                 // targets per slice (32KB LDS A-frags)
#define TILES  (TPS / 32)           // 32 MFMA tiles per slice
#define NSLICE (NPTS / TPS)         // 8
#define QCH    (NPTS / QPB)         // 16
#define GRP    1024                 // targets per slot group (= slice)
#define NGRP   (NPTS / GRP)         // 8
#define FQ     64                   // queries per merge block

typedef __attribute__((ext_vector_type(8)))  short short8;
typedef __attribute__((ext_vector_type(16))) float float16v;

__device__ inline void bsplit(float x, unsigned short& h, unsigned short& l) {
    const unsigned int u = __float_as_uint(x);
    const unsigned short hh = (unsigned short)(u >> 16);   // truncated bf16 hi
    const float lf = x - __uint_as_float((unsigned int)hh << 16);
    h = hh;
    l = (unsigned short)(__float_as_uint(lf) >> 16);       // bf16 lo
}

__device__ inline short8 make_bfrag(float qx, float qy, float qz, int khalf) {
    const float q2 = fmaf(qx, qx, fmaf(qy, qy, qz * qz));
    unsigned short shx, slx, shy, sly, shz, slz, h2q, l2q;
    bsplit(-2.0f * qx, shx, slx); bsplit(-2.0f * qy, shy, sly);
    bsplit(-2.0f * qz, shz, slz); bsplit(q2, h2q, l2q);
    union { short8 v; unsigned short s[8]; } bu;
    if (khalf == 0) {
        bu.s[0]=shx; bu.s[1]=shy; bu.s[2]=shz; bu.s[3]=slx; bu.s[4]=sly; bu.s[5]=slz; bu.s[6]=shx; bu.s[7]=shy;
    } else {
        bu.s[0]=shz; bu.s[1]=0x3F80; bu.s[2]=0x3F80; bu.s[3]=h2q; bu.s[4]=l2q; bu.s[5]=0; bu.s[6]=0; bu.s[7]=0;
    }
    return bu.v;
}

__device__ inline float tree16(const float16v& a) {
    const float t0 = fminf(fminf(a[0],  a[1]),  a[2]);
    const float t1 = fminf(fminf(a[3],  a[4]),  a[5]);
    const float t2 = fminf(fminf(a[6],  a[7]),  a[8]);
    const float t3 = fminf(fminf(a[9],  a[10]), a[11]);
    const float t4 = fminf(fminf(a[12], a[13]), a[14]);
    return fminf(fminf(fminf(t0, t1), a[15]), fminf(fminf(t2, t3), t4));
}

// monotone key: sign-flip map, trunc to 24 value bits, tile id in [4:0].
// bits [7:5] left zero for the group (slice) id (OR'd in by merge A1).
__device__ inline unsigned int packkey(float g, int tl) {
    unsigned int u = __float_as_uint(g);
    u = ((int)u < 0) ? ~u : (u | 0x80000000u);
    return (u & 0xFFFFFF00u) | (unsigned int)tl;
}

__global__ __launch_bounds__(BLK, 4) void dacl_partial(
    const float* __restrict__ gts, const float* __restrict__ preds,
    float* __restrict__ slot, int* __restrict__ cnt, int B, int N)
{
    const int bz  = blockIdx.z;      // dir*B + b
    const int dir = bz / B;
    const int b   = bz - dir * B;
    const int total = 2 * B * N;

    // fold cnt zeroing in (first read by dacl_merge -> boundary orders)
    if (blockIdx.y == 0) {
        const int per = total / (QCH * 2 * B);             // 512
        int* p = cnt + (blockIdx.x + QCH * bz) * per;
        for (int k = threadIdx.x; k < per; k += BLK) p[k] = 0;
    }

    const float* __restrict__ q = (dir == 0 ? gts : preds) + (size_t)b * N * 3;
    const float* __restrict__ t = (dir == 0 ? preds : gts) + (size_t)b * N * 3;

    __shared__ short8 frag[TILES * 64];                    // 32KB A-frags

    // stage+pack A-frags: 1024 targets, 4 per thread.  MFMA K=13 layout:
    // k0-2 thi.(-2qhi)  k3-5 thi.(-2qlo)  k6-8 tlo.(-2qhi)
    // k9 |t|^2hi.1  k10 |t|^2lo.1  k11 1.|q|^2hi  k12 1.|q|^2lo
    const int sbase = blockIdx.y * TPS;
    for (int rep = 0; rep < TPS / BLK; ++rep) {
        const int tgt = rep * BLK + threadIdx.x;
        const int j   = sbase + tgt;
        const float tx = t[3 * j], ty = t[3 * j + 1], tz = t[3 * j + 2];
        const float t2 = fmaf(tx, tx, fmaf(ty, ty, tz * tz));
        unsigned short hx, lx, hy, ly, hz, lz, h2, l2;
        bsplit(tx, hx, lx); bsplit(ty, hy, ly); bsplit(tz, hz, lz); bsplit(t2, h2, l2);
        union { short8 v; unsigned short s[8]; } k0, k1;
        k0.s[0]=hx; k0.s[1]=hy; k0.s[2]=hz; k0.s[3]=hx; k0.s[4]=hy; k0.s[5]=hz; k0.s[6]=lx; k0.s[7]=ly;
        k1.s[0]=lz; k1.s[1]=h2; k1.s[2]=l2; k1.s[3]=0x3F80; k1.s[4]=0x3F80; k1.s[5]=0; k1.s[6]=0; k1.s[7]=0;
        const int tile = tgt >> 5, row = tgt & 31;
        frag[tile * 64 + row]      = k0.v;                 // k-half 0 (lanes 0-31)
        frag[tile * 64 + 32 + row] = k1.v;                 // k-half 1 (lanes 32-63)
    }

    // four B-frags per wave: query cols qiA, +128, +256, +384
    const int lane = threadIdx.x & 63;
    const int wave = threadIdx.x >> 6;
    const int kh   = lane >> 5;
    const int qiA  = blockIdx.x * QPB + wave * 32 + (lane & 31);
    const int qiB  = qiA + 128;
    const int qiC  = qiA + 256;
    const int qiD  = qiA + 384;
    const short8 bfragA = make_bfrag(q[3*qiA], q[3*qiA+1], q[3*qiA+2], kh);
    const short8 bfragB = make_bfrag(q[3*qiB], q[3*qiB+1], q[3*qiB+2], kh);
    const short8 bfragC = make_bfrag(q[3*qiC], q[3*qiC+1], q[3*qiC+2], kh);
    const short8 bfragD = make_bfrag(q[3*qiD], q[3*qiD+1], q[3*qiD+2], kh);

    __syncthreads();

    const float16v zz = {0.f,0.f,0.f,0.f, 0.f,0.f,0.f,0.f,
                         0.f,0.f,0.f,0.f, 0.f,0.f,0.f,0.f};
    const size_t gqA = (size_t)bz * N + qiA;
    unsigned int* __restrict__ slotU = (unsigned int*)slot;
    float gminA = 3.402823466e38f, gminB = 3.402823466e38f;
    float gminC = 3.402823466e38f, gminD = 3.402823466e38f;
    int tlA = 0, tlB = 0, tlC = 0, tlD = 0;

    // hot loop: 1 ds_read_b128 + 4 independent MFMA + 4 min trees per tile;
    // strict-less tile tracking keeps the FIRST (lowest) min tile.
    #pragma unroll 2
    for (int tile = 0; tile < TILES; ++tile) {
        const short8 av = frag[tile * 64 + lane];
        const float16v aA = __builtin_amdgcn_mfma_f32_32x32x16_bf16(av, bfragA, zz, 0, 0, 0);
        const float16v aB = __builtin_amdgcn_mfma_f32_32x32x16_bf16(av, bfragB, zz, 0, 0, 0);
        const float16v aC = __builtin_amdgcn_mfma_f32_32x32x16_bf16(av, bfragC, zz, 0, 0, 0);
        const float16v aD = __builtin_amdgcn_mfma_f32_32x32x16_bf16(av, bfragD, zz, 0, 0, 0);
        const float tA = tree16(aA);
        const float tB = tree16(aB);
        const float tC = tree16(aC);
        const float tD = tree16(aD);
        tlA = (tA < gminA) ? tile : tlA;  gminA = fminf(gminA, tA);
        tlB = (tB < gminB) ? tile : tlB;  gminB = fminf(gminB, tB);
        tlC = (tC < gminC) ? tile : tlC;  gminC = fminf(gminC, tC);
        tlD = (tD < gminD) ? tile : tlD;  gminD = fminf(gminD, tD);
    }

    // close the slice: pack keys, cross-k-half min, one coalesced row store
    {
        const size_t rbase = (size_t)blockIdx.y * total;
        const unsigned int kA = packkey(gminA, tlA);
        const unsigned int kB = packkey(gminB, tlB);
        const unsigned int kC = packkey(gminC, tlC);
        const unsigned int kD = packkey(gminD, tlD);
        const unsigned int oA = min(kA, (unsigned int)__shfl_xor((int)kA, 32, 64));
        const unsigned int oB = min(kB, (unsigned int)__shfl_xor((int)kB, 32, 64));
        const unsigned int oC = min(kC, (unsigned int)__shfl_xor((int)kC, 32, 64));
        const unsigned int oD = min(kD, (unsigned int)__shfl_xor((int)kD, 32, 64));
        if (lane < 32) {
            slotU[rbase + gqA]       = oA;
            slotU[rbase + gqA + 128] = oB;
            slotU[rbase + gqA + 256] = oC;
            slotU[rbase + gqA + 384] = oD;
        }
    }
}

__device__ inline float sq3(float x, float y, float z) {
    return fmaf(x, x, fmaf(y, y, z * z));
}

// 8 exact distances from 6 named float4 (12B per target) — no indexable array
#define DIST8(V0,V1,V2,V3,V4,V5,BASE)                                          \
    do {                                                                       \
        const float d0 = sq3(qx-(V0).x, qy-(V0).y, qz-(V0).z);                 \
        const float d1 = sq3(qx-(V0).w, qy-(V1).x, qz-(V1).y);                 \
        const float d2 = sq3(qx-(V1).z, qy-(V1).w, qz-(V2).x);                 \
        const float d3 = sq3(qx-(V2).y, qy-(V2).z, qz-(V2).w);                 \
        const float d4 = sq3(qx-(V3).x, qy-(V3).y, qz-(V3).z);                 \
        const float d5 = sq3(qx-(V3).w, qy-(V4).x, qz-(V4).y);                 \
        const float d6 = sq3(qx-(V4).z, qy-(V4).w, qz-(V5).x);                 \
        const float d7 = sq3(qx-(V5).y, qy-(V5).z, qz-(V5).w);                 \
        best = min(best, (__float_as_uint(d0) & 0xFFFFFF00u) | (unsigned)((BASE)+0)); \
        best = min(best, (__float_as_uint(d1) & 0xFFFFFF00u) | (unsigned)((BASE)+1)); \
        best = min(best, (__float_as_uint(d2) & 0xFFFFFF00u) | (unsigned)((BASE)+2)); \
        best = min(best, (__float_as_uint(d3) & 0xFFFFFF00u) | (unsigned)((BASE)+3)); \
        best = min(best, (__float_as_uint(d4) & 0xFFFFFF00u) | (unsigned)((BASE)+4)); \
        best = min(best, (__float_as_uint(d5) & 0xFFFFFF00u) | (unsigned)((BASE)+5)); \
        best = min(best, (__float_as_uint(d6) & 0xFFFFFF00u) | (unsigned)((BASE)+6)); \
        best = min(best, (__float_as_uint(d7) & 0xFFFFFF00u) | (unsigned)((BASE)+7)); \
    } while (0)

// A1 + A2 + count; 1024 blocks, 4 workers/query, NO barrier.
// A1: uint min over pre-packed keys | group<<5 -> lexicographic
// (value, group, tile) = first-min order.  A2: exact rescan of the winning
// 32-target tile only (6 float4 + 1 DIST8 per worker).
// Result reuse: d -> slot row 0, idxg -> slot row 1 (rows dead after A1).
__global__ __launch_bounds__(BLK) void dacl_merge(
    const float* __restrict__ gts, const float* __restrict__ preds,
    float* __restrict__ slot, int* __restrict__ cnt,
    float* __restrict__ out, int out_size, int B, int N)
{
    const int tid  = threadIdx.x;
    const int lane = tid & 63;       // local query 0..63
    const int wv   = tid >> 6;       // sub-worker 0..3
    const int total = 2 * B * N;
    const int g0   = blockIdx.x * FQ;                      // first query of block
    const int bz   = g0 / N;                               // block-uniform
    const int dir  = bz / B;
    const int b    = bz - dir * B;
    const float* __restrict__ q = (dir == 0 ? gts : preds) + (size_t)b * N * 3;
    const float* __restrict__ t = (dir == 0 ? preds : gts) + (size_t)b * N * 3;

    __shared__ unsigned int smin[FQ];   // A1: value24 | group3 | tile5
    __shared__ unsigned int skey[FQ];   // A2: bits(d)&~0xFF | idx8

    if (blockIdx.x == 0 && tid < out_size) out[tid] = 0.0f;
    if (tid < FQ) { smin[tid] = 0xFFFFFFFFu; skey[tid] = 0xFFFFFFFFu; }
    __syncthreads();

    const int g = g0 + lane;                               // this query id
    const unsigned int* __restrict__ slotU = (const unsigned int*)slot;

    // A1: wave wv scans group rows [wv*2, wv*2+2); coalesced per row
    {
        unsigned int pk = 0xFFFFFFFFu;
        #pragma unroll
        for (int s = wv * 2; s < wv * 2 + 2; ++s)
            pk = min(pk, slotU[(size_t)s * total + g] | ((unsigned int)s << 5));
        atomicMin(&smin[lane], pk);                        // LDS; ties -> low grp/tile
    }
    __syncthreads();
    const unsigned int sel = smin[lane];
    const int gr = (int)((sel >> 5) & 7u);
    const int tl = (int)(sel & 31u);

    // A2: 4 workers/query, 8 exact targets each over the winning 32-target tile
    const float qx = q[3 * (g - bz * N)], qy = q[3 * (g - bz * N) + 1],
                qz = q[3 * (g - bz * N) + 2];
    {
        const float4* __restrict__ tb4 =
            (const float4*)(t + (size_t)(gr * GRP + tl * 32) * 3) + wv * 6;
        unsigned int best = 0xFFFFFFFFu;
        const float4 v0 = tb4[0];
        const float4 v1 = tb4[1];
        const float4 v2 = tb4[2];
        const float4 v3 = tb4[3];
        const float4 v4 = tb4[4];
        const float4 v5 = tb4[5];
        DIST8(v0, v1, v2, v3, v4, v5, wv * 8);
        atomicMin(&skey[lane], best);                      // LDS; first-min idx
    }
    __syncthreads();

    if (tid < FQ) {
        const unsigned int key = skey[tid];
        const unsigned int sl  = smin[tid];
        const int idxg = (int)((sl >> 5) & 7u) * GRP + (int)(sl & 31u) * 32
                       + (int)(key & 255u);
        slot[g0 + tid]                 = __uint_as_float(key & 0xFFFFFF00u); // d
        ((int*)slot)[total + g0 + tid] = idxg;                               // idx
        atomicAdd(&cnt[bz * N + idxg], 1);
    }
}

__global__ __launch_bounds__(256) void dacl_loss(
    const float* __restrict__ slot, const int* __restrict__ cnt,
    float* __restrict__ out, int B, int N)
{
    const int g  = blockIdx.x * 256 + threadIdx.x;         // query id
    const int total = 2 * B * N;
    const int bz = g / N;
    const int b  = bz - (bz / B) * B;

    const float d   = slot[g];                             // exact (<=2^-16 trunc)
    const int   idx = ((const int*)slot)[total + g];
    const float c   = (float)cnt[bz * N + idx];            // count^1 (lambda=1)
    float sv = 1.0f - expf(-d) / (c + 1e-6f);              // frac terms = 1
    #pragma unroll
    for (int off = 32; off > 0; off >>= 1) sv += __shfl_down(sv, off, 64);
    if ((threadIdx.x & 63) == 0)
        atomicAdd(&out[b], sv / (2.0f * (float)N));        // (mean1+mean2)/2
}

extern "C" void kernel_launch(void* const* d_in, const int* in_sizes, int n_in,
                              void* d_out, int out_size, void* d_ws, size_t ws_size,
                              hipStream_t stream)
{
    const float* gts   = (const float*)d_in[0];
    const float* preds = (const float*)d_in[1];

    const int N = NPTS;
    const int B = in_sizes[0] / (N * 3);                   // = 4

    const size_t nTot = (size_t)2 * B * N;                 // 65536 queries
    float* slot = (float*)d_ws;                            // NGRP x nTot (2.1MB)
    int*   cnt  = (int*)((char*)d_ws + (size_t)NGRP * nTot * sizeof(float));

    dim3 gA(QCH, NSLICE, 2 * B);                           // 16 x 8 x 8 = 1024 blocks
    dacl_partial<<<gA, BLK, 0, stream>>>(gts, preds, slot, cnt, B, N);

    dacl_merge<<<(int)(nTot / FQ), BLK, 0, stream>>>(      // 1024 blocks
        gts, preds, slot, cnt, (float*)d_out, out_size, B, N);

    dacl_loss<<<(int)(nTot / 256), 256, 0, stream>>>(      // 256 blocks
        slot, cnt, (float*)d_out, B, N);
}